// Round 7
// baseline (708.399 us; speedup 1.0000x reference)
//
#include <hip/hip_runtime.h>
#include <hip/hip_fp16.h>

#define CH 64
#define PSH 8            // 256 dsts per partition
#define PSZ 256
#define CAPP 4096        // per-partition edge capacity (mean 3277, ~14 sigma headroom)
#define TILE 2048        // edges per part_kernel block
#define EPT 8            // edges per thread
#define RANGE 12500      // outdeg-histogram bins per block (50 KB LDS)
#define SLICES 16
#define SPILLMAX 4096

// ---------------- pass 1: bin edges by dst-partition (two-phase LDS) --------
__global__ __launch_bounds__(256) void part_kernel(const int* __restrict__ src,
                                                   const int* __restrict__ dst,
                                                   int* __restrict__ pcursor,
                                                   int* __restrict__ part_edges,
                                                   int* __restrict__ spill,
                                                   int* __restrict__ nspill,
                                                   int E, int P)
{
    __shared__ int hist[512];
    __shared__ int base[512];
    int tid = threadIdx.x;
    int e0 = blockIdx.x * TILE + tid * EPT;
    int s[EPT], d[EPT];
    int nk = 0;
    if (e0 + EPT <= E) {
        const int4* sp = (const int4*)(src + e0);
        const int4* dp = (const int4*)(dst + e0);
        int4 a = sp[0], b = sp[1], c = dp[0], f = dp[1];
        s[0]=a.x; s[1]=a.y; s[2]=a.z; s[3]=a.w; s[4]=b.x; s[5]=b.y; s[6]=b.z; s[7]=b.w;
        d[0]=c.x; d[1]=c.y; d[2]=c.z; d[3]=c.w; d[4]=f.x; d[5]=f.y; d[6]=f.z; d[7]=f.w;
        nk = EPT;
    } else {
        for (int k = 0; e0 + k < E && k < EPT; ++k) { s[k] = src[e0+k]; d[k] = dst[e0+k]; nk++; }
    }
    for (int i = tid; i < P; i += 256) hist[i] = 0;
    __syncthreads();
    for (int k = 0; k < nk; ++k) atomicAdd(&hist[d[k] >> PSH], 1);
    __syncthreads();
    for (int i = tid; i < P; i += 256) {
        int c = hist[i];
        base[i] = c ? atomicAdd(&pcursor[i], c) : 0;   // 1 atomic per (tile,part)
        hist[i] = 0;                                   // reuse as local cursor
    }
    __syncthreads();
    for (int k = 0; k < nk; ++k) {
        int p = d[k] >> PSH;
        int r = atomicAdd(&hist[p], 1);
        int pos = base[p] + r;
        if (pos < CAPP) {
            part_edges[(size_t)p * CAPP + pos] = (s[k] << PSH) | (d[k] & (PSZ - 1));
        } else {   // statistically never
            int sp2 = atomicAdd(nspill, 1);
            if (sp2 < SPILLMAX) { spill[2*sp2] = d[k]; spill[2*sp2+1] = s[k]; }
        }
    }
}

// ---------------- outdeg: privatized LDS histograms -> partials -------------
__global__ __launch_bounds__(256) void odeg_hist_kernel(const int* __restrict__ src,
                                                        int* __restrict__ partial,
                                                        int E, int N, int R)
{
    __shared__ int h[RANGE];
    int r  = blockIdx.x % R;
    int sl = blockIdx.x / R;
    int lo = r * RANGE;
    int hi = min(lo + RANGE, N);
    int span = hi - lo;
    for (int i = threadIdx.x; i < span; i += 256) h[i] = 0;
    __syncthreads();
    int per = (E + SLICES - 1) / SLICES;
    int sb = sl * per, se = min(sb + per, E);
    for (int e = sb + threadIdx.x; e < se; e += 256) {
        int sv = src[e];
        if (sv >= lo && sv < hi) atomicAdd(&h[sv - lo], 1);
    }
    __syncthreads();
    int* pp = partial + (size_t)blockIdx.x * RANGE;
    for (int i = threadIdx.x; i < span; i += 256) pp[i] = h[i];
}

__global__ __launch_bounds__(256) void odeg_reduce_kernel(const int* __restrict__ partial,
                                                          int* __restrict__ outdeg,
                                                          int N, int R)
{
    int n = blockIdx.x * 256 + threadIdx.x;
    if (n >= N) return;
    int r = n / RANGE, off = n - r * RANGE;
    int s = 0;
    for (int sl = 0; sl < SLICES; ++sl)
        s += partial[(size_t)(sl * R + r) * RANGE + off];
    outdeg[n] = s;
}

// ---------------- prescale: xh[n] = rsqrt(outdeg[n]) * x[n]  (fp16) ---------
__global__ __launch_bounds__(256) void prescale_kernel(const float* __restrict__ x,
                                                       const int* __restrict__ outdeg,
                                                       __half* __restrict__ xh, int N)
{
    int g = blockIdx.x * blockDim.x + threadIdx.x;
    int total = N * (CH / 8);
    if (g >= total) return;
    int node = g >> 3, sub = g & 7;
    int od = outdeg[node];
    float ns = (od > 0) ? rsqrtf((float)od) : 0.0f;
    const float4* xp = (const float4*)(x + (size_t)node * CH + sub * 8);
    float4 a = xp[0], b = xp[1];
    __half2 h0 = __floats2half2_rn(a.x * ns, a.y * ns);
    __half2 h1 = __floats2half2_rn(a.z * ns, a.w * ns);
    __half2 h2 = __floats2half2_rn(b.x * ns, b.y * ns);
    __half2 h3 = __floats2half2_rn(b.z * ns, b.w * ns);
    uint4 u;
    u.x = (unsigned)__half_as_ushort(h0.x) | ((unsigned)__half_as_ushort(h0.y) << 16);
    u.y = (unsigned)__half_as_ushort(h1.x) | ((unsigned)__half_as_ushort(h1.y) << 16);
    u.z = (unsigned)__half_as_ushort(h2.x) | ((unsigned)__half_as_ushort(h2.y) << 16);
    u.w = (unsigned)__half_as_ushort(h3.x) | ((unsigned)__half_as_ushort(h3.y) << 16);
    *(uint4*)(xh + (size_t)node * CH + sub * 8) = u;
}

// ---------------- per-partition aggregate into LDS fp32 ---------------------
__device__ __forceinline__ void accum32(const __half* __restrict__ xh, int sv, int half,
                                        int dl, float* acc)
{
    const uint4* xq = (const uint4*)(xh + (size_t)sv * CH + half * 32);
    int sw = dl & 31;
    float* ar = acc + dl * 32;
    #pragma unroll
    for (int q = 0; q < 4; ++q) {
        uint4 u = xq[q];
        float2 f0 = __half22float2(*reinterpret_cast<const __half2*>(&u.x));
        float2 f1 = __half22float2(*reinterpret_cast<const __half2*>(&u.y));
        float2 f2 = __half22float2(*reinterpret_cast<const __half2*>(&u.z));
        float2 f3 = __half22float2(*reinterpret_cast<const __half2*>(&u.w));
        int cb = q * 8;
        atomicAdd(&ar[(cb+0)^sw], f0.x); atomicAdd(&ar[(cb+1)^sw], f0.y);
        atomicAdd(&ar[(cb+2)^sw], f1.x); atomicAdd(&ar[(cb+3)^sw], f1.y);
        atomicAdd(&ar[(cb+4)^sw], f2.x); atomicAdd(&ar[(cb+5)^sw], f2.y);
        atomicAdd(&ar[(cb+6)^sw], f3.x); atomicAdd(&ar[(cb+7)^sw], f3.y);
    }
}

// grid = 2*P blocks: block handles (partition p = bid>>1, channel-half = bid&1)
__global__ __launch_bounds__(256) void agg_part_kernel(const __half* __restrict__ xh,
                                                       const int* __restrict__ part_edges,
                                                       const int* __restrict__ pcursor,
                                                       const int* __restrict__ spill,
                                                       const int* __restrict__ nspill,
                                                       __half* __restrict__ aggh, int N)
{
    __shared__ float acc[PSZ * 32];
    __shared__ int cnt[PSZ];
    int bid = blockIdx.x;
    int half = bid & 1;
    int p = bid >> 1;
    int pbase = p << PSH;
    int tid = threadIdx.x;
    for (int i = tid; i < PSZ * 32; i += 256) acc[i] = 0.0f;
    for (int i = tid; i < PSZ; i += 256) cnt[i] = 0;
    __syncthreads();
    int m = pcursor[p];
    int mc = (m < CAPP) ? m : CAPP;
    const int* lp = part_edges + (size_t)p * CAPP;
    for (int j = tid; j < mc; j += 256) {
        int v = lp[j];
        int sv = v >> PSH;
        int dl = v & (PSZ - 1);
        atomicAdd(&cnt[dl], 1);
        accum32(xh, sv, half, dl, acc);
    }
    int ns = *nspill;                      // cold path, 0 on this data
    if (ns > 0) {
        if (ns > SPILLMAX) ns = SPILLMAX;
        for (int i = tid; i < ns; i += 256) {
            int dfull = spill[2*i];
            if ((dfull >> PSH) == p) {
                int sv = spill[2*i+1];
                int dl = dfull & (PSZ - 1);
                atomicAdd(&cnt[dl], 1);
                accum32(xh, sv, half, dl, acc);
            }
        }
    }
    __syncthreads();
    for (int i = tid; i < PSZ * 16; i += 256) {    // 16 half2 per dst per half
        int dl = i >> 4;
        int c2 = (i & 15) * 2;
        int node = pbase + dl;
        if (node >= N) continue;
        int c = cnt[dl];
        float nd = (c > 0) ? rsqrtf((float)c) : 0.0f;
        int sw = dl & 31;
        float fx = acc[dl * 32 + ((c2    ) ^ sw)] * nd;
        float fy = acc[dl * 32 + ((c2 + 1) ^ sw)] * nd;
        *(__half2*)(aggh + (size_t)node * CH + half * 32 + c2) = __floats2half2_rn(fx, fy);
    }
}

// ---------------- out = aggh @ W + bias  (row per thread, W scalarized) -----
__global__ __launch_bounds__(256) void gemm_out_kernel(const __half* __restrict__ aggh,
                                                       const float* __restrict__ W,
                                                       const float* __restrict__ bias,
                                                       float* __restrict__ out, int N)
{
    int row = blockIdx.x * blockDim.x + threadIdx.x;
    if (row >= N) return;
    float xr[CH];
    const __half2* xp = (const __half2*)(aggh + (size_t)row * CH);
    #pragma unroll
    for (int j = 0; j < CH / 2; ++j) {
        float2 f = __half22float2(xp[j]);
        xr[2 * j + 0] = f.x;
        xr[2 * j + 1] = f.y;
    }
    float* op = out + (size_t)row * CH;
    for (int c0 = 0; c0 < CH; c0 += 16) {
        float acc[16];
        #pragma unroll
        for (int q = 0; q < 16; ++q) acc[q] = 0.0f;
        #pragma unroll 8
        for (int k = 0; k < CH; ++k) {
            const float xk = xr[k];
            #pragma unroll
            for (int q = 0; q < 4; ++q) {
                float4 w = *(const float4*)(W + k * CH + c0 + q * 4);  // wave-uniform -> s_load
                acc[q * 4 + 0] += xk * w.x;
                acc[q * 4 + 1] += xk * w.y;
                acc[q * 4 + 2] += xk * w.z;
                acc[q * 4 + 3] += xk * w.w;
            }
        }
        #pragma unroll
        for (int q = 0; q < 4; ++q) {
            float4 b = *(const float4*)(bias + c0 + q * 4);
            float4 o;
            o.x = acc[q * 4 + 0] + b.x;
            o.y = acc[q * 4 + 1] + b.y;
            o.z = acc[q * 4 + 2] + b.z;
            o.w = acc[q * 4 + 3] + b.w;
            *(float4*)(op + c0 + q * 4) = o;
        }
    }
}

extern "C" void kernel_launch(void* const* d_in, const int* in_sizes, int n_in,
                              void* d_out, int out_size, void* d_ws, size_t ws_size,
                              hipStream_t stream)
{
    const float* x    = (const float*)d_in[0];
    const int*   edge = (const int*)d_in[1];
    const float* W    = (const float*)d_in[2];
    const float* bias = (const float*)d_in[3];
    float* out = (float*)d_out;

    int N = in_sizes[0] / CH;   // 100000
    int E = in_sizes[1] / 2;    // 1280000
    const int* src = edge;
    const int* dst = edge + E;
    int P = (N + PSZ - 1) >> PSH;            // 391
    int R = (N + RANGE - 1) / RANGE;         // 8

    // workspace layout (ints 4B):
    // [pcursor 512][nspill@512, pad][spill 2*SPILLMAX @576][part_edges P*CAPP]
    // [partial SLICES*R*RANGE][outdeg N][align][xh N*CH halves][align][aggh N*CH halves]
    int* pcursor    = (int*)d_ws;
    int* nspill     = pcursor + 512;
    int* spill      = pcursor + 576;
    int* part_edges = pcursor + 576 + 2 * SPILLMAX;
    int* partial    = part_edges + (size_t)P * CAPP;
    int* outdeg     = partial + (size_t)SLICES * R * RANGE;
    size_t xoff = (((char*)(outdeg + N) - (char*)d_ws) + 255) & ~(size_t)255;
    __half* xh = (__half*)((char*)d_ws + xoff);
    size_t aoff = ((xoff + (size_t)N * CH * sizeof(__half)) + 255) & ~(size_t)255;
    __half* aggh = (__half*)((char*)d_ws + aoff);

    hipMemsetAsync(pcursor, 0, 640 * sizeof(int), stream);   // pcursor + nspill

    part_kernel<<<(E + TILE - 1) / TILE, 256, 0, stream>>>(src, dst, pcursor, part_edges,
                                                           spill, nspill, E, P);
    odeg_hist_kernel<<<R * SLICES, 256, 0, stream>>>(src, partial, E, N, R);
    odeg_reduce_kernel<<<(N + 255) / 256, 256, 0, stream>>>(partial, outdeg, N, R);
    prescale_kernel<<<(N * (CH / 8) + 255) / 256, 256, 0, stream>>>(x, outdeg, xh, N);
    agg_part_kernel<<<2 * P, 256, 0, stream>>>(xh, part_edges, pcursor, spill, nspill, aggh, N);
    gemm_out_kernel<<<(N + 255) / 256, 256, 0, stream>>>(aggh, W, bias, out, N);
}